// Round 7
// baseline (624.407 us; speedup 1.0000x reference)
//
#include <hip/hip_runtime.h>
#include <hip/hip_bf16.h>
#include <math.h>

typedef __hip_bfloat16 bf16;
typedef __bf16 bf16x8 __attribute__((ext_vector_type(8)));
typedef float f32x4 __attribute__((ext_vector_type(4)));

#define B_ 8
#define T_ 2048
#define D_ 512
#define H_ 2048

__device__ __forceinline__ float b2f(unsigned short u) {
    return __uint_as_float((unsigned)u << 16);
}
__device__ __forceinline__ float ldf(const float* p, long i) { return p[i]; }
__device__ __forceinline__ float ldf(const bf16* p, long i) {
    return b2f(((const unsigned short*)p)[i]);
}
// tanh-form gelu: v*sigmoid(1.59577(v+0.044715 v^3)); |err| < 1e-3 abs
__device__ __forceinline__ float gelu_f(float v) {
    float a = 1.5957691216057308f * (v + 0.044715f * v * v * v);
    return v / (1.0f + __expf(-a));
}

// Packed (tile-major) layout for ALL GEMM operands:
// tile = 16 rows x 32 cols (1 KB bf16) = one MFMA fragment-group; within-tile
// offset = (row&15)*32 + (col&31); tiles row-strip-major then k.
//   off(row,col,K) = ((row>>4)*(K>>5) + (col>>5))*512 + (row&15)*32 + (col&31)
// Staging (LDS path) reads 1KB contiguous bursts; NOLDS path reads each lane's
// fragment DIRECTLY from global (wave covers exactly one 1KB tile per load).
__device__ __forceinline__ long poff(int row, int col, int K) {
    return ((long)(row >> 4) * (K >> 5) + (col >> 5)) * 512 + (row & 15) * 32 + (col & 31);
}

#define GLD16(g, l)                                                          \
    __builtin_amdgcn_global_load_lds(                                        \
        (const __attribute__((address_space(1))) void*)(g),                  \
        (__attribute__((address_space(3))) void*)(l), 16, 0, 0)

// ---------------- LayerNorm over D=512, one block (256 thr) per row ----------------
template <typename Tin, bool PACKO>
__global__ __launch_bounds__(256) void ln_kernel(const Tin* __restrict__ x,
                                                 const float* __restrict__ g,
                                                 const float* __restrict__ bb,
                                                 bf16* __restrict__ y) {
    int row = blockIdx.x;
    long base = (long)row * D_;
    int tid = threadIdx.x;
    float v0 = ldf(x, base + tid);
    float v1 = ldf(x, base + tid + 256);
    float s = v0 + v1;
#pragma unroll
    for (int off = 32; off > 0; off >>= 1) s += __shfl_down(s, off);
    __shared__ float red[4];
    int lane = tid & 63, wid = tid >> 6;
    if (lane == 0) red[wid] = s;
    __syncthreads();
    float mean = (red[0] + red[1] + red[2] + red[3]) * (1.0f / 512.0f);
    __syncthreads();
    float d0 = v0 - mean, d1 = v1 - mean;
    float vs = d0 * d0 + d1 * d1;
#pragma unroll
    for (int off = 32; off > 0; off >>= 1) vs += __shfl_down(vs, off);
    if (lane == 0) red[wid] = vs;
    __syncthreads();
    float var = (red[0] + red[1] + red[2] + red[3]) * (1.0f / 512.0f);
    float rstd = rsqrtf(var + 1e-5f);
    float o0 = d0 * rstd * g[tid] + bb[tid];
    float o1 = d1 * rstd * g[tid + 256] + bb[tid + 256];
    if (PACKO) {
        y[poff(row, tid, D_)]       = __float2bfloat16(o0);
        y[poff(row, tid + 256, D_)] = __float2bfloat16(o1);
    } else {
        y[base + tid]       = __float2bfloat16(o0);
        y[base + tid + 256] = __float2bfloat16(o1);
    }
}

// ---------------- exp(w - rowmax(w)) : one block per row; PACKED output ----------
__global__ __launch_bounds__(256) void expw_kernel(const float* __restrict__ w,
                                                   bf16* __restrict__ ew) {
    int row = blockIdx.x;
    long base = (long)row * T_;
    int tid = threadIdx.x;
    float v[8];
    float mx = -3.4e38f;
#pragma unroll
    for (int i = 0; i < 8; ++i) {
        v[i] = w[base + tid + i * 256];
        mx = fmaxf(mx, v[i]);
    }
#pragma unroll
    for (int off = 32; off > 0; off >>= 1) mx = fmaxf(mx, __shfl_down(mx, off));
    __shared__ float red[4];
    if ((tid & 63) == 0) red[tid >> 6] = mx;
    __syncthreads();
    float rmax = fmaxf(fmaxf(red[0], red[1]), fmaxf(red[2], red[3]));
#pragma unroll
    for (int i = 0; i < 8; ++i)
        ew[poff(row, tid + i * 256, T_)] = __float2bfloat16(expf(v[i] - rmax));
}

// ------ max over batch dim of K [B][packed TD] -> mk[packed TD] (f32) ------------
// elementwise over the packed index: layout-agnostic as long as kv2t agrees.
__global__ __launch_bounds__(256) void maxk_kernel(const bf16* __restrict__ K,
                                                   float* __restrict__ mk) {
    long i = (long)blockIdx.x * 256 + threadIdx.x;
    float m = ldf(K, i);
#pragma unroll
    for (int b = 1; b < B_; ++b) m = fmaxf(m, ldf(K, (long)b * (T_ * D_) + i));
    mk[i] = m;
}

// ------- build kv2T[b][n][t] PACKED (K=T_): n<512: expK*V; n>=512: expK ----------
// K_,V_ are PACKED [T,D] per batch; mk indexed by the same packed offset.
__global__ __launch_bounds__(256) void kv2t_kernel(const bf16* __restrict__ K_,
                                                   const bf16* __restrict__ V_,
                                                   const float* __restrict__ mk,
                                                   bf16* __restrict__ kv2t) {
    __shared__ float sev[64][65];
    __shared__ float se[64][65];
    int tx = threadIdx.x & 63, ty = threadIdx.x >> 6;
    int t0 = blockIdx.x * 64, d0 = blockIdx.y * 64, b = blockIdx.z;
    long ibase = (long)b << 20;
#pragma unroll
    for (int r = 0; r < 16; ++r) {
        int tl = r * 4 + ty;
        long pi = poff(t0 + tl, d0 + tx, D_);
        float e = expf(ldf(K_, ibase + pi) - mk[pi]);
        sev[tl][tx] = e * ldf(V_, ibase + pi);
        se[tl][tx] = e;
    }
    __syncthreads();
    long obase = (long)b << 21;
#pragma unroll
    for (int r = 0; r < 16; ++r) {
        int dl = r * 4 + ty;
        kv2t[obase + poff(d0 + dl, t0 + tx, T_)]       = __float2bfloat16(sev[tx][dl]);
        kv2t[obase + poff(512 + d0 + dl, t0 + tx, T_)] = __float2bfloat16(se[tx][dl]);
    }
}

// -------- Yt = sigQ * num/den, in place on PACKED sigQ; nd is linear [T,1024] -----
__global__ __launch_bounds__(256) void yt_kernel(const bf16* __restrict__ nd,
                                                 bf16* __restrict__ q) {
    long i = (long)blockIdx.x * 256 + threadIdx.x;
    long b = i >> 20;
    long p = i & (long)(T_ * D_ - 1);
    int tile = (int)(p >> 9);
    int ro = (int)((p >> 5) & 15);
    int cs = (int)(p & 31);
    int t = (tile >> 4) * 16 + ro;   // 16 tiles per row-strip (D=512)
    int d = (tile & 15) * 32 + cs;
    long base = (b << 21) + ((long)t << 10);
    float num = ldf(nd, base + d), den = ldf(nd, base + 512 + d);
    q[i] = __float2bfloat16(ldf(q, i) * num / den);
}

// -------- batched weight transpose + f32->bf16: W[K,N] -> WT[N,K] PACKED ----------
struct WT6 {
    const float* src[6];
    bf16* dst[6];
    int K[6], N[6];
};
__global__ __launch_bounds__(256) void wtrans6_kernel(WT6 p) {
    int z = blockIdx.z;
    int K = p.K[z], N = p.N[z];
    int n0 = blockIdx.x * 64, k0 = blockIdx.y * 64;
    if (n0 >= N || k0 >= K) return;
    const float* W = p.src[z];
    bf16* WT = p.dst[z];
    __shared__ float s[64][65];
    int tx = threadIdx.x & 63, ty = threadIdx.x >> 6;
#pragma unroll
    for (int r = 0; r < 16; ++r) {
        int kl = r * 4 + ty;
        s[kl][tx] = W[(long)(k0 + kl) * N + n0 + tx];
    }
    __syncthreads();
#pragma unroll
    for (int r = 0; r < 16; ++r) {
        int nl = r * 4 + ty;
        WT[poff(n0 + nl, k0 + tx, K)] = __float2bfloat16(s[tx][nl]);
    }
}

// ---------------- MFMA GEMM: C = epi(A@Bt^T + bias) [+res] ------------------------
// All operands PACKED. Two K-loop bodies:
//  NL=true (K=512 GEMMs + step 12): NO LDS, NO barriers. Each lane loads its MFMA
//    fragment straight from packed global (wave = one coalesced 1KB tile per load);
//    operand panels are L2-resident (128KB/block; weights 2-8MB/XCD with swizzle).
//    Eliminates the 2-phase stage->vmcnt(0)->barrier stall (m233: 72% of critical
//    path) entirely; latency hidden by 12 waves/CU free-running TLP. LB (256,3).
//  NL=false (step 7, working set > L2): proven R6 2-buffer LDS loop. LB (256,4).
// PCK: C written packed (non-plane path). Plane path (step 3) ALWAYS writes packed.
// XCD swizzle: 3D chunked remap over (x,y,z).
template <int BM, bool NL, int PCK>
__global__ __launch_bounds__(256, NL ? 3 : 4) void mfma_gemm(
    const bf16* __restrict__ A, const bf16* __restrict__ Bt,
    const float* __restrict__ b0, const float* __restrict__ b1,
    const float* __restrict__ b2,
    bf16* __restrict__ Cb, float* __restrict__ Cf,
    const bf16* __restrict__ resb, const float* __restrict__ resf,
    int M, int N, int K, int modes, long bsB, long bsC, long planeStride) {
    constexpr int MI = BM / 32;           // 4
    constexpr int NA = BM / 64;           // 2
    constexpr int PL = (BM + 128) * 32;   // shorts per LDS buffer plane
    __shared__ short Sh[NL ? 16 : 2 * PL];
    int tid = threadIdx.x;
    int lane = tid & 63, wave = tid >> 6;
    int wm = wave & 1, wn = wave >> 1;

    // 3D chunked XCD swizzle (nwg % 8 == 0 for every launch here)
    int gx = gridDim.x, gy = gridDim.y;
    long nwg = (long)gx * gy * gridDim.z;
    long o = blockIdx.x + (long)gx * (blockIdx.y + (long)gy * blockIdx.z);
    long wk = (o & 7) * (nwg >> 3) + (o >> 3);
    int bx = (int)(wk % gx);
    long rq = wk / gx;
    int by = (int)(rq % gy);
    int bz = (int)(rq / gy);
    int m0 = by * BM, n0 = bx * 128;

    const short* Ag = (const short*)A;
    const short* Bg = (const short*)Bt + (long)bz * bsB;

    int fr = lane & 15;
    int fk = (lane >> 4) * 8;
    int rm = wm * (BM / 2);

    f32x4 acc[MI][4];
    f32x4 zz = {0.f, 0.f, 0.f, 0.f};
#pragma unroll
    for (int i = 0; i < MI; ++i)
#pragma unroll
        for (int j = 0; j < 4; ++j) acc[i][j] = zz;

    if constexpr (NL) {
        // ---- direct-from-global fragment loads, barrier-free K loop ----
        const long ts = (long)K << 4;           // shorts per 16-row strip
        const int lo = fr * 32 + fk;            // lane's within-tile short offset
        const short* Aw = Ag + (long)((m0 >> 4) + wm * MI) * ts + lo;
        const short* Bw = Bg + (long)((n0 >> 4) + wn * 4) * ts + lo;
        int nk = K >> 5;
#pragma unroll 2
        for (int kt = 0; kt < nk; ++kt) {
            bf16x8 af[MI], bv[4];
            long ko = (long)kt * 512;
#pragma unroll
            for (int mi = 0; mi < MI; ++mi)
                af[mi] = *(const bf16x8*)(Aw + (long)mi * ts + ko);
#pragma unroll
            for (int ni = 0; ni < 4; ++ni)
                bv[ni] = *(const bf16x8*)(Bw + (long)ni * ts + ko);
#pragma unroll
            for (int mi = 0; mi < MI; ++mi)
#pragma unroll
                for (int ni = 0; ni < 4; ++ni)
                    acc[mi][ni] = __builtin_amdgcn_mfma_f32_16x16x32_bf16(
                        af[mi], bv[ni], acc[mi][ni], 0, 0, 0);
        }
    } else {
        // ---- proven 2-buffer LDS loop (packed staging, 1KB bursts) ----
        const short* ga[NA];
        short* la[NA];
#pragma unroll
        for (int i = 0; i < NA; ++i) {
            int arow = m0 + wave * (BM / 4) + i * 16;
            ga[i] = Ag + (long)(arow >> 4) * ((long)K << 4) + lane * 8;
            la[i] = Sh + (wave * (BM / 4) + i * 16) * 32;
        }
        int brow = n0 + wave * 32;
        const short* gb0 = Bg + (long)(brow >> 4) * ((long)K << 4) + lane * 8;
        const short* gb1 = gb0 + ((long)K << 4);
        short* lb0 = Sh + BM * 32 + (wave * 32) * 32;
        short* lb1 = lb0 + 16 * 32;

        auto stage = [&](int kt, int ofs) {
#pragma unroll
            for (int i = 0; i < NA; ++i) GLD16(ga[i] + (long)kt * 512, la[i] + ofs);
            GLD16(gb0 + (long)kt * 512, lb0 + ofs);
            GLD16(gb1 + (long)kt * 512, lb1 + ofs);
        };
        auto compute = [&](int ofs) {
            const short* Asb = Sh + ofs;
            const short* Bsb = Sh + ofs + BM * 32;
            bf16x8 af[MI], bv[4];
#pragma unroll
            for (int mi = 0; mi < MI; ++mi)
                af[mi] = *(const bf16x8*)(Asb + (rm + mi * 16 + fr) * 32 + fk);
#pragma unroll
            for (int ni = 0; ni < 4; ++ni)
                bv[ni] = *(const bf16x8*)(Bsb + (wn * 64 + ni * 16 + fr) * 32 + fk);
#pragma unroll
            for (int mi = 0; mi < MI; ++mi)
#pragma unroll
                for (int ni = 0; ni < 4; ++ni)
                    acc[mi][ni] = __builtin_amdgcn_mfma_f32_16x16x32_bf16(
                        af[mi], bv[ni], acc[mi][ni], 0, 0, 0);
        };

        int nk = K >> 5;
        stage(0, 0);
        __syncthreads();
        for (int kt = 0; kt < nk; kt += 2) {
            if (kt + 1 < nk) stage(kt + 1, PL);
            compute(0);
            __syncthreads();
            if (kt + 2 < nk) stage(kt + 2, 0);
            compute(PL);
            __syncthreads();
        }
    }

    int cc = lane & 15, cr = (lane >> 4) * 4;
    long cbase = (long)bz * bsC;
#pragma unroll
    for (int mi = 0; mi < MI; ++mi) {
#pragma unroll
        for (int ni = 0; ni < 4; ++ni) {
            int row0 = m0 + rm + mi * 16 + cr;
            int col = n0 + wn * 64 + ni * 16 + cc;
            float bvl;
            int md;
            int plane = 0, c2 = col;
            if (planeStride) {
                plane = col >> 9;
                c2 = col & 511;
                const float* bp = (plane == 0) ? b0 : ((plane == 1) ? b1 : b2);
                bvl = bp[c2];
                md = (modes >> (2 * plane)) & 3;
            } else {
                bvl = b0 ? b0[col] : 0.0f;
                md = modes & 3;
            }
#pragma unroll
            for (int r = 0; r < 4; ++r) {
                float v = acc[mi][ni][r] + bvl;
                if (md == 1) v = 1.0f / (1.0f + __expf(-v));
                else if (md == 2) v = gelu_f(v);
                long idx;
                if (planeStride) idx = (long)plane * planeStride + poff(row0 + r, c2, 512);
                else if (PCK)    idx = cbase + poff(row0 + r, col, N);
                else             idx = cbase + (long)(row0 + r) * N + col;
                if (resf) v += resf[idx];
                if (resb) v += ldf(resb, idx);
                if (Cf) Cf[idx] = v;
                else Cb[idx] = __float2bfloat16(v);
            }
        }
    }
}

extern "C" void kernel_launch(void* const* d_in, const int* in_sizes, int n_in,
                              void* d_out, int out_size, void* d_ws, size_t ws_size,
                              hipStream_t stream) {
    const float* x    = (const float*)d_in[0];
    const float* ln1g = (const float*)d_in[1];
    const float* ln1b = (const float*)d_in[2];
    const float* Wk   = (const float*)d_in[3];
    const float* bk   = (const float*)d_in[4];
    const float* Wv   = (const float*)d_in[5];
    const float* bv   = (const float*)d_in[6];
    const float* Wq   = (const float*)d_in[7];
    const float* bq   = (const float*)d_in[8];
    const float* w    = (const float*)d_in[9];
    const float* Wo   = (const float*)d_in[10];
    const float* bo   = (const float*)d_in[11];
    const float* ln2g = (const float*)d_in[12];
    const float* ln2b = (const float*)d_in[13];
    const float* W1   = (const float*)d_in[14];
    const float* b1   = (const float*)d_in[15];
    const float* W2   = (const float*)d_in[16];
    const float* b2   = (const float*)d_in[17];
    float* out = (float*)d_out;

    const long S_BTD = (long)B_ * T_ * D_;      // 8,388,608
    const long S_TD  = (long)T_ * D_;           // 1,048,576
    const long S_TT  = (long)T_ * T_;           // 4,194,304
    const long S_B2D = (long)B_ * T_ * 2 * D_;  // 16,777,216
    const long S_DD  = (long)D_ * D_;           // 262,144

    // Workspace (bf16 elems unless noted) ~136 MB:
    bf16* h1     = (bf16*)d_ws;            // later h2 (both PACKED)
    bf16* outres = h1 + S_BTD;             // linear
    bf16* ew     = outres + S_BTD;         // PACKED
    bf16* KVQ    = ew + S_TT;              // K|V|Q planes (3*S_BTD), PACKED
    bf16* kv2t   = KVQ + 3 * S_BTD;        // S_B2D, PACKED per batch
    float* mk    = (float*)(kv2t + S_B2D); // S_TD f32 (packed-indexed)
    bf16* WkT    = (bf16*)(mk + S_TD);     // all weights PACKED
    bf16* WvT    = WkT + S_DD;
    bf16* WqT    = WvT + S_DD;
    bf16* WoT    = WqT + S_DD;
    bf16* W1T    = WoT + S_DD;             // [H,D]
    bf16* W2T    = W1T + (long)D_ * H_;    // [D,H]
    bf16* Kb  = KVQ;
    bf16* Vb  = KVQ + S_BTD;
    bf16* Qb  = KVQ + 2 * S_BTD;           // sigQ packed, then Yt in place
    bf16* nd  = KVQ;                       // linear; overwrites K|V after kv2t
    bf16* hH  = KVQ;                       // PACKED; spans KVQ+kv2t
    bf16* h2  = h1;

    const int M = B_ * T_;  // 16384

    // 1. batched weight transposes (packed output)
    WT6 p;
    p.src[0] = Wk; p.src[1] = Wv; p.src[2] = Wq; p.src[3] = Wo; p.src[4] = W1; p.src[5] = W2;
    p.dst[0] = WkT; p.dst[1] = WvT; p.dst[2] = WqT; p.dst[3] = WoT; p.dst[4] = W1T; p.dst[5] = W2T;
    p.K[0] = p.K[1] = p.K[2] = p.K[3] = 512; p.K[4] = 512; p.K[5] = 2048;
    p.N[0] = p.N[1] = p.N[2] = p.N[3] = 512; p.N[4] = 2048; p.N[5] = 512;
    wtrans6_kernel<<<dim3(32, 32, 6), 256, 0, stream>>>(p);
    // 2. h1 = LN1(x), packed
    ln_kernel<float, true><<<M, 256, 0, stream>>>(x, ln1g, ln1b, h1);
    // 3. K|V|sigQ GEMM (NOLDS): planes written PACKED to Kb,Vb,Qb
    mfma_gemm<128, true, 0><<<dim3(1536 / 128, M / 128, 1), 256, 0, stream>>>(
        h1, WkT, bk, bv, bq, Kb, nullptr, nullptr, nullptr,
        M, 1536, D_, (1 << 4), 0, 0, S_BTD);
    // 4. mk = max_b K (packed-elementwise); 5. kv2t packed
    maxk_kernel<<<S_TD / 256, 256, 0, stream>>>(Kb, mk);
    kv2t_kernel<<<dim3(T_ / 64, D_ / 64, B_), 256, 0, stream>>>(Kb, Vb, mk, kv2t);
    // 6. exp_w (packed)
    expw_kernel<<<T_, 256, 0, stream>>>(w, ew);
    // 7. nd[b] = ew @ kv2t[b]^T (LDS path: working set > L2), out linear
    mfma_gemm<128, false, 0><<<dim3(1024 / 128, T_ / 128, B_), 256, 0, stream>>>(
        ew, kv2t, nullptr, nullptr, nullptr, nd, nullptr, nullptr, nullptr,
        T_, 1024, T_, 0, (long)1024 * T_, (long)T_ * 1024, 0);
    // 8. Yt = sigQ * num/den (in place on packed Qb)
    yt_kernel<<<S_BTD / 256, 256, 0, stream>>>(nd, Qb);
    // 9. out = Yt@Wo + bo + x (NOLDS), C linear + f32 residual
    mfma_gemm<128, true, 0><<<dim3(D_ / 128, M / 128, 1), 256, 0, stream>>>(
        Qb, WoT, bo, nullptr, nullptr, outres, nullptr, nullptr, x,
        M, D_, D_, 0, 0, 0, 0);
    // 10. h2 = LN2(out), packed
    ln_kernel<bf16, true><<<M, 256, 0, stream>>>(outres, ln2g, ln2b, h2);
    // 11. hH = gelu(h2@W1 + b1) (NOLDS), C PACKED (= step-12 A)
    mfma_gemm<128, true, 4><<<dim3(H_ / 128, M / 128, 1), 256, 0, stream>>>(
        h2, W1T, b1, nullptr, nullptr, hH, nullptr, nullptr, nullptr,
        M, H_, D_, 2, 0, 0, 0);
    // 12. y = gelu(hH@W2 + b2) + out -> f32 d_out (NOLDS)
    mfma_gemm<128, true, 0><<<dim3(D_ / 128, M / 128, 1), 256, 0, stream>>>(
        hH, W2T, b2, nullptr, nullptr, nullptr, out, outres, nullptr,
        M, D_, H_, 2, 0, 0, 0);
}

// Round 8
// 509.767 us; speedup vs baseline: 1.2249x; 1.2249x over previous
//
#include <hip/hip_runtime.h>
#include <hip/hip_bf16.h>
#include <math.h>

typedef __hip_bfloat16 bf16;
typedef __bf16 bf16x8 __attribute__((ext_vector_type(8)));
typedef float f32x4 __attribute__((ext_vector_type(4)));

#define B_ 8
#define T_ 2048
#define D_ 512
#define H_ 2048

__device__ __forceinline__ float b2f(unsigned short u) {
    return __uint_as_float((unsigned)u << 16);
}
__device__ __forceinline__ float ldf(const float* p, long i) { return p[i]; }
__device__ __forceinline__ float ldf(const bf16* p, long i) {
    return b2f(((const unsigned short*)p)[i]);
}
// tanh-form gelu: v*sigmoid(1.59577(v+0.044715 v^3)); |err| < 1e-3 abs
__device__ __forceinline__ float gelu_f(float v) {
    float a = 1.5957691216057308f * (v + 0.044715f * v * v * v);
    return v / (1.0f + __expf(-a));
}

// Packed (tile-major) layout for GEMM-staged operands:
// tile = 16 rows x 32 cols (1 KB bf16) = exactly one wave's global_load_lds
// payload in LDS dest order: within-tile offset = (row&15)*32 + (col&31).
//   off(row,col,K) = ((row>>4)*(K>>5) + (col>>5))*512 + (row&15)*32 + (col&31)
// => staging is fully-contiguous 1KB bursts (FETCH 138->25MB measured, R5).
__device__ __forceinline__ long poff(int row, int col, int K) {
    return ((long)(row >> 4) * (K >> 5) + (col >> 5)) * 512 + (row & 15) * 32 + (col & 31);
}

#define GLD16(g, l)                                                          \
    __builtin_amdgcn_global_load_lds(                                        \
        (const __attribute__((address_space(1))) void*)(g),                  \
        (__attribute__((address_space(3))) void*)(l), 16, 0, 0)

// ---------------- LayerNorm over D=512, one block (256 thr) per row ----------------
template <typename Tin, bool PACKO>
__global__ __launch_bounds__(256) void ln_kernel(const Tin* __restrict__ x,
                                                 const float* __restrict__ g,
                                                 const float* __restrict__ bb,
                                                 bf16* __restrict__ y) {
    int row = blockIdx.x;
    long base = (long)row * D_;
    int tid = threadIdx.x;
    float v0 = ldf(x, base + tid);
    float v1 = ldf(x, base + tid + 256);
    float s = v0 + v1;
#pragma unroll
    for (int off = 32; off > 0; off >>= 1) s += __shfl_down(s, off);
    __shared__ float red[4];
    int lane = tid & 63, wid = tid >> 6;
    if (lane == 0) red[wid] = s;
    __syncthreads();
    float mean = (red[0] + red[1] + red[2] + red[3]) * (1.0f / 512.0f);
    __syncthreads();
    float d0 = v0 - mean, d1 = v1 - mean;
    float vs = d0 * d0 + d1 * d1;
#pragma unroll
    for (int off = 32; off > 0; off >>= 1) vs += __shfl_down(vs, off);
    if (lane == 0) red[wid] = vs;
    __syncthreads();
    float var = (red[0] + red[1] + red[2] + red[3]) * (1.0f / 512.0f);
    float rstd = rsqrtf(var + 1e-5f);
    float o0 = d0 * rstd * g[tid] + bb[tid];
    float o1 = d1 * rstd * g[tid + 256] + bb[tid + 256];
    if (PACKO) {
        y[poff(row, tid, D_)]       = __float2bfloat16(o0);
        y[poff(row, tid + 256, D_)] = __float2bfloat16(o1);
    } else {
        y[base + tid]       = __float2bfloat16(o0);
        y[base + tid + 256] = __float2bfloat16(o1);
    }
}

// ---------------- exp(w - rowmax(w)) : one block per row; PACKED output ----------
__global__ __launch_bounds__(256) void expw_kernel(const float* __restrict__ w,
                                                   bf16* __restrict__ ew) {
    int row = blockIdx.x;
    long base = (long)row * T_;
    int tid = threadIdx.x;
    float v[8];
    float mx = -3.4e38f;
#pragma unroll
    for (int i = 0; i < 8; ++i) {
        v[i] = w[base + tid + i * 256];
        mx = fmaxf(mx, v[i]);
    }
#pragma unroll
    for (int off = 32; off > 0; off >>= 1) mx = fmaxf(mx, __shfl_down(mx, off));
    __shared__ float red[4];
    if ((tid & 63) == 0) red[tid >> 6] = mx;
    __syncthreads();
    float rmax = fmaxf(fmaxf(red[0], red[1]), fmaxf(red[2], red[3]));
#pragma unroll
    for (int i = 0; i < 8; ++i)
        ew[poff(row, tid + i * 256, T_)] = __float2bfloat16(expf(v[i] - rmax));
}

// ---- max over batch dim of K [B,T,D] -> mk [T*D] (bf16: max of bf16 is exact) ----
__global__ __launch_bounds__(256) void maxk_kernel(const bf16* __restrict__ K,
                                                   bf16* __restrict__ mk) {
    long i = (long)blockIdx.x * 256 + threadIdx.x;
    float m = ldf(K, i);
#pragma unroll
    for (int b = 1; b < B_; ++b) m = fmaxf(m, ldf(K, (long)b * (T_ * D_) + i));
    mk[i] = __float2bfloat16(m);
}

// ------- build kv2T[b][n][t] PACKED (K=T_): n<512: expK*V (d=n); n>=512: expK -----
__global__ __launch_bounds__(256) void kv2t_kernel(const bf16* __restrict__ K_,
                                                   const bf16* __restrict__ V_,
                                                   const bf16* __restrict__ mk,
                                                   bf16* __restrict__ kv2t) {
    __shared__ float sev[64][65];
    __shared__ float se[64][65];
    int tx = threadIdx.x & 63, ty = threadIdx.x >> 6;
    int t0 = blockIdx.x * 64, d0 = blockIdx.y * 64, b = blockIdx.z;
    long ibase = (long)b << 20;
#pragma unroll
    for (int r = 0; r < 16; ++r) {
        int tl = r * 4 + ty;
        long mi = (long)(t0 + tl) * D_ + d0 + tx;
        float e = expf(ldf(K_, ibase + mi) - ldf(mk, mi));
        sev[tl][tx] = e * ldf(V_, ibase + mi);
        se[tl][tx] = e;
    }
    __syncthreads();
    long obase = (long)b << 21;
#pragma unroll
    for (int r = 0; r < 16; ++r) {
        int dl = r * 4 + ty;
        kv2t[obase + poff(d0 + dl, t0 + tx, T_)]       = __float2bfloat16(sev[tx][dl]);
        kv2t[obase + poff(512 + d0 + dl, t0 + tx, T_)] = __float2bfloat16(se[tx][dl]);
    }
}

// ---------------- Yt = sigQ * num/den, in place on sigQ (linear) ----------------
__global__ __launch_bounds__(256) void yt_kernel(const bf16* __restrict__ nd,
                                                 bf16* __restrict__ q) {
    long i = (long)blockIdx.x * 256 + threadIdx.x;
    long td = i & (long)(T_ * D_ - 1);
    long b = i >> 20;
    long t = td >> 9;
    long d = td & (D_ - 1);
    long base = (b << 21) + (t << 10);
    float num = ldf(nd, base + d), den = ldf(nd, base + D_ + d);
    q[i] = __float2bfloat16(ldf(q, i) * num / den);
}

// -------- batched weight transpose + f32->bf16: W[K,N] -> WT[N,K] PACKED ----------
struct WT6 {
    const float* src[6];
    bf16* dst[6];
    int K[6], N[6];
};
__global__ __launch_bounds__(256) void wtrans6_kernel(WT6 p) {
    int z = blockIdx.z;
    int K = p.K[z], N = p.N[z];
    int n0 = blockIdx.x * 64, k0 = blockIdx.y * 64;
    if (n0 >= N || k0 >= K) return;
    const float* W = p.src[z];
    bf16* WT = p.dst[z];
    __shared__ float s[64][65];
    int tx = threadIdx.x & 63, ty = threadIdx.x >> 6;
#pragma unroll
    for (int r = 0; r < 16; ++r) {
        int kl = r * 4 + ty;
        s[kl][tx] = W[(long)(k0 + kl) * N + n0 + tx];
    }
    __syncthreads();
#pragma unroll
    for (int r = 0; r < 16; ++r) {
        int nl = r * 4 + ty;
        WT[poff(n0 + nl, k0 + tx, K)] = __float2bfloat16(s[tx][nl]);
    }
}

// ---------------- MFMA GEMM: C = epi(A@Bt^T + bias) [+res] ------------------------
// 128 x 128 macro-tile, 4 waves, 2-buffer LDS for A, __syncthreads per K-step.
// R7 ablation + counters give the port model: R6's hot GEMM was LDS-PORT-bound
// (96KB ds_read + 48KB DMA-write per CU-step ~1100-1500cy vs 310cy MFMA), and
// R7's all-global variant was L2-VECTOR-bound (96KB @~56B/cy ~1700cy). So:
//  BD=1 (B = L2-resident weight panel; s3/s9/s11/s12): A via LDS dbuf (proven),
//    B fragments loaded DIRECTLY from packed global into regs. Halves LDS reads,
//    drops 2 of 6 stage DMAs; plain reg loads are NOT drained by __syncthreads,
//    so they pipeline across barriers. Traffic split across both ports.
//  BD=0 (s7: B=kv2t, 4MB/batch): byte-identical R6 path.
// PK bit0: A packed; bit1: B packed (required if BD); bit2: C written packed.
// XCD swizzle: 3D chunked remap over (x,y,z) (nwg%8==0 for all launches).
// planeStride!=0: N split into 512-col planes; per-plane bias b0/b1/b2 and
// mode=(modes>>(2*plane))&3. mode 0=none 1=sigmoid 2=gelu.
template <int BM, int PK, int BD>
__global__ __launch_bounds__(256, 4) void mfma_gemm(
    const bf16* __restrict__ A, const bf16* __restrict__ Bt,
    const float* __restrict__ b0, const float* __restrict__ b1,
    const float* __restrict__ b2,
    bf16* __restrict__ Cb, float* __restrict__ Cf,
    const bf16* __restrict__ resb, const float* __restrict__ resf,
    int M, int N, int K, int modes, long bsB, long bsC, long planeStride) {
    constexpr int MI = BM / 32;
    constexpr int NA = BM / 64;
    constexpr int PLL = BD ? BM * 32 : (BM + 128) * 32;  // shorts per LDS buffer
    constexpr bool PA = PK & 1, PB = PK & 2, PCK = PK & 4;
    static_assert(!BD || PB, "BD requires packed B");
    constexpr long astep = PA ? 512 : 32;
    constexpr long bstep = PB ? 512 : 32;
    __shared__ short Sh[2 * PLL];
    int tid = threadIdx.x;
    int lane = tid & 63, wave = tid >> 6;
    int wm = wave & 1, wn = wave >> 1;

    // 3D chunked XCD swizzle (nwg % 8 == 0 for every launch here)
    int gx = gridDim.x, gy = gridDim.y;
    long nwg = (long)gx * gy * gridDim.z;
    long o = blockIdx.x + (long)gx * (blockIdx.y + (long)gy * blockIdx.z);
    long wk = (o & 7) * (nwg >> 3) + (o >> 3);
    int bx = (int)(wk % gx);
    long rq = wk / gx;
    int by = (int)(rq % gy);
    int bz = (int)(rq / gy);
    int m0 = by * BM, n0 = bx * 128;

    const short* Ag = (const short*)A;
    const short* Bg = (const short*)Bt + (long)bz * bsB;

    int lr = lane >> 2;
    int le = (lane & 3) * 8;
    const short* ga[NA];
    short* la[NA];
#pragma unroll
    for (int i = 0; i < NA; ++i) {
        int arow = m0 + wave * (BM / 4) + i * 16;
        ga[i] = PA ? Ag + (long)(arow >> 4) * ((long)K << 4) + lane * 8
                   : Ag + (long)(arow + lr) * K + le;
        la[i] = Sh + (wave * (BM / 4) + i * 16) * 32;
    }

    int fr = lane & 15;
    int fk = (lane >> 4) * 8;
    int rm = wm * (BM / 2);

    // B addressing: BD -> per-lane fragment pointer into packed global;
    //               else -> staging pointers into LDS region.
    const long ts = (long)K << 4;  // shorts per 16-row packed strip
    const short* Bw = Bg + (long)((n0 >> 4) + wn * 4) * ts + fr * 32 + fk;
    int brow = n0 + wave * 32;
    const short* gb0 = PB ? Bg + (long)(brow >> 4) * ts + lane * 8
                          : Bg + (long)(brow + lr) * K + le;
    const short* gb1 = PB ? gb0 + ts : gb0 + 16L * K;
    short* lb0 = Sh + BM * 32 + (wave * 32) * 32;
    short* lb1 = lb0 + 16 * 32;

    f32x4 acc[MI][4];
    f32x4 zz = {0.f, 0.f, 0.f, 0.f};
#pragma unroll
    for (int i = 0; i < MI; ++i)
#pragma unroll
        for (int j = 0; j < 4; ++j) acc[i][j] = zz;

    auto stage = [&](int kt, int ofs) {
#pragma unroll
        for (int i = 0; i < NA; ++i) GLD16(ga[i] + kt * astep, la[i] + ofs);
        if constexpr (!BD) {
            GLD16(gb0 + kt * bstep, lb0 + ofs);
            GLD16(gb1 + kt * bstep, lb1 + ofs);
        }
    };
    auto compute = [&](int ofs, int kt) {
        const short* Asb = Sh + ofs;
        bf16x8 af[MI], bv[4];
#pragma unroll
        for (int mi = 0; mi < MI; ++mi)
            af[mi] = *(const bf16x8*)(Asb + (rm + mi * 16 + fr) * 32 + fk);
        if constexpr (BD) {
#pragma unroll
            for (int ni = 0; ni < 4; ++ni)
                bv[ni] = *(const bf16x8*)(Bw + (long)ni * ts + (long)kt * 512);
        } else {
            const short* Bsb = Sh + ofs + BM * 32;
#pragma unroll
            for (int ni = 0; ni < 4; ++ni)
                bv[ni] = *(const bf16x8*)(Bsb + (wn * 64 + ni * 16 + fr) * 32 + fk);
        }
#pragma unroll
        for (int mi = 0; mi < MI; ++mi)
#pragma unroll
            for (int ni = 0; ni < 4; ++ni)
                acc[mi][ni] = __builtin_amdgcn_mfma_f32_16x16x32_bf16(
                    af[mi], bv[ni], acc[mi][ni], 0, 0, 0);
    };

    // ---- 2-buffer pipelined K loop (nk even for all shapes used: K=512/2048) ----
    int nk = K >> 5;
    stage(0, 0);
    __syncthreads();
    for (int kt = 0; kt < nk; kt += 2) {
        if (kt + 1 < nk) stage(kt + 1, PLL);
        compute(0, kt);
        __syncthreads();
        if (kt + 2 < nk) stage(kt + 2, 0);
        compute(PLL, kt + 1);
        __syncthreads();
    }

    int cc = lane & 15, cr = (lane >> 4) * 4;
    long cbase = (long)bz * bsC;
#pragma unroll
    for (int mi = 0; mi < MI; ++mi) {
#pragma unroll
        for (int ni = 0; ni < 4; ++ni) {
            int row0 = m0 + rm + mi * 16 + cr;
            int col = n0 + wn * 64 + ni * 16 + cc;
            float bvl;
            long colterm;
            int md, rowstride;
            if (planeStride) {
                int plane = col >> 9;
                int c2 = col & 511;
                const float* bp = (plane == 0) ? b0 : ((plane == 1) ? b1 : b2);
                bvl = bp[c2];
                md = (modes >> (2 * plane)) & 3;
                colterm = (long)plane * planeStride + c2;
                rowstride = 512;
            } else {
                bvl = b0 ? b0[col] : 0.0f;
                md = modes & 3;
                colterm = col;
                rowstride = N;
            }
#pragma unroll
            for (int r = 0; r < 4; ++r) {
                float v = acc[mi][ni][r] + bvl;
                if (md == 1) v = 1.0f / (1.0f + __expf(-v));
                else if (md == 2) v = gelu_f(v);
                long idx;
                if (PCK) idx = cbase + poff(row0 + r, col, N);
                else     idx = cbase + (long)(row0 + r) * rowstride + colterm;
                if (resf) v += resf[idx];
                if (resb) v += ldf(resb, idx);
                if (Cf) Cf[idx] = v;
                else Cb[idx] = __float2bfloat16(v);
            }
        }
    }
}

extern "C" void kernel_launch(void* const* d_in, const int* in_sizes, int n_in,
                              void* d_out, int out_size, void* d_ws, size_t ws_size,
                              hipStream_t stream) {
    const float* x    = (const float*)d_in[0];
    const float* ln1g = (const float*)d_in[1];
    const float* ln1b = (const float*)d_in[2];
    const float* Wk   = (const float*)d_in[3];
    const float* bk   = (const float*)d_in[4];
    const float* Wv   = (const float*)d_in[5];
    const float* bv   = (const float*)d_in[6];
    const float* Wq   = (const float*)d_in[7];
    const float* bq   = (const float*)d_in[8];
    const float* w    = (const float*)d_in[9];
    const float* Wo   = (const float*)d_in[10];
    const float* bo   = (const float*)d_in[11];
    const float* ln2g = (const float*)d_in[12];
    const float* ln2b = (const float*)d_in[13];
    const float* W1   = (const float*)d_in[14];
    const float* b1   = (const float*)d_in[15];
    const float* W2   = (const float*)d_in[16];
    const float* b2   = (const float*)d_in[17];
    float* out = (float*)d_out;

    const long S_BTD = (long)B_ * T_ * D_;      // 8,388,608
    const long S_TD  = (long)T_ * D_;           // 1,048,576
    const long S_TT  = (long)T_ * T_;           // 4,194,304
    const long S_B2D = (long)B_ * T_ * 2 * D_;  // 16,777,216
    const long S_DD  = (long)D_ * D_;           // 262,144

    // Workspace (bf16 elems unless noted) ~136 MB:
    bf16* h1     = (bf16*)d_ws;            // later h2 (both PACKED)
    bf16* outres = h1 + S_BTD;             // linear
    bf16* ew     = outres + S_BTD;         // PACKED
    bf16* KVQ    = ew + S_TT;              // K|V|Q planes (3*S_BTD), linear
    bf16* kv2t   = KVQ + 3 * S_BTD;        // S_B2D, PACKED per batch
    bf16* mk     = kv2t + S_B2D;           // S_TD bf16 (in old f32 slot)
    bf16* WkT    = mk + 2 * S_TD;          // all weights PACKED
    bf16* WvT    = WkT + S_DD;
    bf16* WqT    = WvT + S_DD;
    bf16* WoT    = WqT + S_DD;
    bf16* W1T    = WoT + S_DD;             // [H,D]
    bf16* W2T    = W1T + (long)D_ * H_;    // [D,H]
    bf16* Kb  = KVQ;
    bf16* Vb  = KVQ + S_BTD;
    bf16* Qb  = KVQ + 2 * S_BTD;           // sigQ, then Yt in place (linear)
    bf16* nd  = KVQ;                       // linear; overwrites K|V after kv2t
    bf16* hH  = KVQ;                       // PACKED; spans KVQ+kv2t
    bf16* h2  = h1;

    const int M = B_ * T_;  // 16384

    // 1. batched weight transposes (packed output)
    WT6 p;
    p.src[0] = Wk; p.src[1] = Wv; p.src[2] = Wq; p.src[3] = Wo; p.src[4] = W1; p.src[5] = W2;
    p.dst[0] = WkT; p.dst[1] = WvT; p.dst[2] = WqT; p.dst[3] = WoT; p.dst[4] = W1T; p.dst[5] = W2T;
    p.K[0] = p.K[1] = p.K[2] = p.K[3] = 512; p.K[4] = 512; p.K[5] = 2048;
    p.N[0] = p.N[1] = p.N[2] = p.N[3] = 512; p.N[4] = 2048; p.N[5] = 512;
    wtrans6_kernel<<<dim3(32, 32, 6), 256, 0, stream>>>(p);
    // 2. h1 = LN1(x), packed
    ln_kernel<float, true><<<M, 256, 0, stream>>>(x, ln1g, ln1b, h1);
    // 3. K|V|sigQ GEMM (A packed via LDS, B-direct): planes linear -> Kb,Vb,Qb
    mfma_gemm<128, 3, 1><<<dim3(1536 / 128, M / 128, 1), 256, 0, stream>>>(
        h1, WkT, bk, bv, bq, Kb, nullptr, nullptr, nullptr,
        M, 1536, D_, (1 << 4), 0, 0, S_BTD);
    // 4. mk = max_b K (bf16); 5. kv2t packed
    maxk_kernel<<<S_TD / 256, 256, 0, stream>>>(Kb, mk);
    kv2t_kernel<<<dim3(T_ / 64, D_ / 64, B_), 256, 0, stream>>>(Kb, Vb, mk, kv2t);
    // 6. exp_w (packed)
    expw_kernel<<<T_, 256, 0, stream>>>(w, ew);
    // 7. nd[b] = ew @ kv2t[b]^T (full LDS path: B too large for B-direct), linear
    mfma_gemm<128, 3, 0><<<dim3(1024 / 128, T_ / 128, B_), 256, 0, stream>>>(
        ew, kv2t, nullptr, nullptr, nullptr, nd, nullptr, nullptr, nullptr,
        T_, 1024, T_, 0, (long)1024 * T_, (long)T_ * 1024, 0);
    // 8. Yt = sigQ * num/den (in place on Qb, linear)
    yt_kernel<<<S_BTD / 256, 256, 0, stream>>>(nd, Qb);
    // 9. out = Yt@Wo + bo + x (A linear via LDS, B-direct), C linear + f32 residual
    mfma_gemm<128, 2, 1><<<dim3(D_ / 128, M / 128, 1), 256, 0, stream>>>(
        Qb, WoT, bo, nullptr, nullptr, outres, nullptr, nullptr, x,
        M, D_, D_, 0, 0, 0, 0);
    // 10. h2 = LN2(out), packed
    ln_kernel<bf16, true><<<M, 256, 0, stream>>>(outres, ln2g, ln2b, h2);
    // 11. hH = gelu(h2@W1 + b1) (A packed via LDS, B-direct), C PACKED (= s12 A)
    mfma_gemm<128, 7, 1><<<dim3(H_ / 128, M / 128, 1), 256, 0, stream>>>(
        h2, W1T, b1, nullptr, nullptr, hH, nullptr, nullptr, nullptr,
        M, H_, D_, 2, 0, 0, 0);
    // 12. y = gelu(hH@W2 + b2) + out -> f32 d_out (A packed via LDS, B-direct)
    mfma_gemm<128, 3, 1><<<dim3(D_ / 128, M / 128, 1), 256, 0, stream>>>(
        hH, W2T, b2, nullptr, nullptr, nullptr, out, outres, nullptr,
        M, D_, H_, 2, 0, 0, 0);
}

// Round 9
// 486.359 us; speedup vs baseline: 1.2838x; 1.0481x over previous
//
#include <hip/hip_runtime.h>
#include <hip/hip_bf16.h>
#include <math.h>

typedef __hip_bfloat16 bf16;
typedef __bf16 bf16x8 __attribute__((ext_vector_type(8)));
typedef float f32x4 __attribute__((ext_vector_type(4)));

#define B_ 8
#define T_ 2048
#define D_ 512
#define H_ 2048

__device__ __forceinline__ float b2f(unsigned short u) {
    return __uint_as_float((unsigned)u << 16);
}
__device__ __forceinline__ float ldf(const float* p, long i) { return p[i]; }
__device__ __forceinline__ float ldf(const bf16* p, long i) {
    return b2f(((const unsigned short*)p)[i]);
}
// tanh-form gelu: v*sigmoid(1.59577(v+0.044715 v^3)); |err| < 1e-3 abs
__device__ __forceinline__ float gelu_f(float v) {
    float a = 1.5957691216057308f * (v + 0.044715f * v * v * v);
    return v / (1.0f + __expf(-a));
}

// Packed (tile-major) layout for GEMM-staged operands:
// tile = 16 rows x 32 cols (1 KB bf16) = exactly one wave's global_load_lds
// payload in LDS dest order: within-tile offset = (row&15)*32 + (col&31).
//   off(row,col,K) = ((row>>4)*(K>>5) + (col>>5))*512 + (row&15)*32 + (col&31)
// => staging is fully-contiguous 1KB bursts (FETCH 138->25MB measured, R5).
__device__ __forceinline__ long poff(int row, int col, int K) {
    return ((long)(row >> 4) * (K >> 5) + (col >> 5)) * 512 + (row & 15) * 32 + (col & 31);
}

#define GLD16(g, l)                                                          \
    __builtin_amdgcn_global_load_lds(                                        \
        (const __attribute__((address_space(1))) void*)(g),                  \
        (__attribute__((address_space(3))) void*)(l), 16, 0, 0)

// ---------------- LayerNorm over D=512, one block (256 thr) per row ----------------
template <typename Tin, bool PACKO>
__global__ __launch_bounds__(256) void ln_kernel(const Tin* __restrict__ x,
                                                 const float* __restrict__ g,
                                                 const float* __restrict__ bb,
                                                 bf16* __restrict__ y) {
    int row = blockIdx.x;
    long base = (long)row * D_;
    int tid = threadIdx.x;
    float v0 = ldf(x, base + tid);
    float v1 = ldf(x, base + tid + 256);
    float s = v0 + v1;
#pragma unroll
    for (int off = 32; off > 0; off >>= 1) s += __shfl_down(s, off);
    __shared__ float red[4];
    int lane = tid & 63, wid = tid >> 6;
    if (lane == 0) red[wid] = s;
    __syncthreads();
    float mean = (red[0] + red[1] + red[2] + red[3]) * (1.0f / 512.0f);
    __syncthreads();
    float d0 = v0 - mean, d1 = v1 - mean;
    float vs = d0 * d0 + d1 * d1;
#pragma unroll
    for (int off = 32; off > 0; off >>= 1) vs += __shfl_down(vs, off);
    if (lane == 0) red[wid] = vs;
    __syncthreads();
    float var = (red[0] + red[1] + red[2] + red[3]) * (1.0f / 512.0f);
    float rstd = rsqrtf(var + 1e-5f);
    float o0 = d0 * rstd * g[tid] + bb[tid];
    float o1 = d1 * rstd * g[tid + 256] + bb[tid + 256];
    if (PACKO) {
        y[poff(row, tid, D_)]       = __float2bfloat16(o0);
        y[poff(row, tid + 256, D_)] = __float2bfloat16(o1);
    } else {
        y[base + tid]       = __float2bfloat16(o0);
        y[base + tid + 256] = __float2bfloat16(o1);
    }
}

// ---------------- exp(w - rowmax(w)) : one block per row; PACKED output ----------
__global__ __launch_bounds__(256) void expw_kernel(const float* __restrict__ w,
                                                   bf16* __restrict__ ew) {
    int row = blockIdx.x;
    long base = (long)row * T_;
    int tid = threadIdx.x;
    float v[8];
    float mx = -3.4e38f;
#pragma unroll
    for (int i = 0; i < 8; ++i) {
        v[i] = w[base + tid + i * 256];
        mx = fmaxf(mx, v[i]);
    }
#pragma unroll
    for (int off = 32; off > 0; off >>= 1) mx = fmaxf(mx, __shfl_down(mx, off));
    __shared__ float red[4];
    if ((tid & 63) == 0) red[tid >> 6] = mx;
    __syncthreads();
    float rmax = fmaxf(fmaxf(red[0], red[1]), fmaxf(red[2], red[3]));
#pragma unroll
    for (int i = 0; i < 8; ++i)
        ew[poff(row, tid + i * 256, T_)] = __float2bfloat16(expf(v[i] - rmax));
}

// ---- max over batch dim of K [B,T,D] -> mk [T*D] (bf16: max of bf16 is exact) ----
__global__ __launch_bounds__(256) void maxk_kernel(const bf16* __restrict__ K,
                                                   bf16* __restrict__ mk) {
    long i = (long)blockIdx.x * 256 + threadIdx.x;
    float m = ldf(K, i);
#pragma unroll
    for (int b = 1; b < B_; ++b) m = fmaxf(m, ldf(K, (long)b * (T_ * D_) + i));
    mk[i] = __float2bfloat16(m);
}

// ------- build kv2T[b][n][t] PACKED, INTERLEAVED rows: n=2d -> expK*V (num),
// n=2d+1 -> expK (den). Adjacent output cols in s7 => num/den in adjacent lanes,
// enabling the fused-Yt epilogue (shfl_xor(.,1)) that eliminates yt_kernel.
__global__ __launch_bounds__(256) void kv2t_kernel(const bf16* __restrict__ K_,
                                                   const bf16* __restrict__ V_,
                                                   const bf16* __restrict__ mk,
                                                   bf16* __restrict__ kv2t) {
    __shared__ float sev[64][65];
    __shared__ float se[64][65];
    int tx = threadIdx.x & 63, ty = threadIdx.x >> 6;
    int t0 = blockIdx.x * 64, d0 = blockIdx.y * 64, b = blockIdx.z;
    long ibase = (long)b << 20;
#pragma unroll
    for (int r = 0; r < 16; ++r) {
        int tl = r * 4 + ty;
        long mi = (long)(t0 + tl) * D_ + d0 + tx;
        float e = expf(ldf(K_, ibase + mi) - ldf(mk, mi));
        sev[tl][tx] = e * ldf(V_, ibase + mi);
        se[tl][tx] = e;
    }
    __syncthreads();
    long obase = (long)b << 21;
#pragma unroll
    for (int r = 0; r < 16; ++r) {
        int dl = r * 4 + ty;
        int nrow = 2 * (d0 + dl);
        kv2t[obase + poff(nrow,     t0 + tx, T_)] = __float2bfloat16(sev[tx][dl]);
        kv2t[obase + poff(nrow + 1, t0 + tx, T_)] = __float2bfloat16(se[tx][dl]);
    }
}

// -------- batched weight transpose + f32->bf16: W[K,N] -> WT[N,K] PACKED ----------
struct WT6 {
    const float* src[6];
    bf16* dst[6];
    int K[6], N[6];
};
__global__ __launch_bounds__(256) void wtrans6_kernel(WT6 p) {
    int z = blockIdx.z;
    int K = p.K[z], N = p.N[z];
    int n0 = blockIdx.x * 64, k0 = blockIdx.y * 64;
    if (n0 >= N || k0 >= K) return;
    const float* W = p.src[z];
    bf16* WT = p.dst[z];
    __shared__ float s[64][65];
    int tx = threadIdx.x & 63, ty = threadIdx.x >> 6;
#pragma unroll
    for (int r = 0; r < 16; ++r) {
        int kl = r * 4 + ty;
        s[kl][tx] = W[(long)(k0 + kl) * N + n0 + tx];
    }
    __syncthreads();
#pragma unroll
    for (int r = 0; r < 16; ++r) {
        int nl = r * 4 + ty;
        WT[poff(n0 + nl, k0 + tx, K)] = __float2bfloat16(s[tx][nl]);
    }
}

// ---------------- MFMA GEMM: C = epi(A@Bt^T + bias) [+res] ------------------------
// R6-proven body: 128x128 macro-tile, 4 waves, 2-buffer LDS, plain C++ LDS reads,
// __syncthreads per K-step, packed 1KB-burst staging, 3D chunked XCD swizzle.
// (R7/R8 ablations: moving either operand to direct-global regressed — LDS-DMA +
// multi-block TLP is the best schedule for this 2-phase structure; keep it.)
// yq != null (s7 only): FUSED-Yt epilogue. B rows are interleaved num/den pairs;
// lane holds num (even col) or den (odd col); den fetched via __shfl_xor(v,1);
// writes Yt = sigQ*num/den IN PLACE into yq (linear [B,T,D]). Skips C write.
// PK bit0: A packed; bit1: B packed; bit2: C written packed (non-plane path).
// planeStride!=0: N split into 512-col planes; per-plane bias b0/b1/b2 and
// mode=(modes>>(2*plane))&3. mode 0=none 1=sigmoid 2=gelu.
template <int BM, int PK>
__global__ __launch_bounds__(256, 4) void mfma_gemm(
    const bf16* __restrict__ A, const bf16* __restrict__ Bt,
    const float* __restrict__ b0, const float* __restrict__ b1,
    const float* __restrict__ b2,
    bf16* __restrict__ Cb, float* __restrict__ Cf,
    const bf16* __restrict__ resb, const float* __restrict__ resf,
    bf16* __restrict__ yq,
    int M, int N, int K, int modes, long bsB, long bsC, long planeStride) {
    constexpr int MI = BM / 32;
    constexpr int NA = BM / 64;
    constexpr int PL = (BM + 128) * 32;  // shorts per LDS buffer plane
    constexpr bool PA = PK & 1, PB = PK & 2, PCK = PK & 4;
    constexpr long astep = PA ? 512 : 32;
    constexpr long bstep = PB ? 512 : 32;
    __shared__ short Sh[2 * PL];         // 2 bufs: 32KB @BM=128
    int tid = threadIdx.x;
    int lane = tid & 63, wave = tid >> 6;
    int wm = wave & 1, wn = wave >> 1;

    // 3D chunked XCD swizzle (nwg % 8 == 0 for every launch here)
    int gx = gridDim.x, gy = gridDim.y;
    long nwg = (long)gx * gy * gridDim.z;
    long o = blockIdx.x + (long)gx * (blockIdx.y + (long)gy * blockIdx.z);
    long wk = (o & 7) * (nwg >> 3) + (o >> 3);
    int bx = (int)(wk % gx);
    long rq = wk / gx;
    int by = (int)(rq % gy);
    int bz = (int)(rq / gy);
    int m0 = by * BM, n0 = bx * 128;

    const short* Ag = (const short*)A;
    const short* Bg = (const short*)Bt + (long)bz * bsB;

    int lr = lane >> 2;
    int le = (lane & 3) * 8;
    const short* ga[NA];
    short* la[NA];
#pragma unroll
    for (int i = 0; i < NA; ++i) {
        int arow = m0 + wave * (BM / 4) + i * 16;
        ga[i] = PA ? Ag + (long)(arow >> 4) * ((long)K << 4) + lane * 8
                   : Ag + (long)(arow + lr) * K + le;
        la[i] = Sh + (wave * (BM / 4) + i * 16) * 32;
    }
    int brow = n0 + wave * 32;
    const short* gb0 = PB ? Bg + (long)(brow >> 4) * ((long)K << 4) + lane * 8
                          : Bg + (long)(brow + lr) * K + le;
    const short* gb1 = PB ? gb0 + ((long)K << 4) : gb0 + 16L * K;
    short* lb0 = Sh + BM * 32 + (wave * 32) * 32;
    short* lb1 = lb0 + 16 * 32;

    f32x4 acc[MI][4];
    f32x4 zz = {0.f, 0.f, 0.f, 0.f};
#pragma unroll
    for (int i = 0; i < MI; ++i)
#pragma unroll
        for (int j = 0; j < 4; ++j) acc[i][j] = zz;

    int fr = lane & 15;
    int fk = (lane >> 4) * 8;
    int rm = wm * (BM / 2);

    auto stage = [&](int kt, int ofs) {
#pragma unroll
        for (int i = 0; i < NA; ++i) GLD16(ga[i] + kt * astep, la[i] + ofs);
        GLD16(gb0 + kt * bstep, lb0 + ofs);
        GLD16(gb1 + kt * bstep, lb1 + ofs);
    };
    auto compute = [&](int ofs) {
        const short* Asb = Sh + ofs;
        const short* Bsb = Sh + ofs + BM * 32;
        bf16x8 af[MI], bv[4];
#pragma unroll
        for (int mi = 0; mi < MI; ++mi)
            af[mi] = *(const bf16x8*)(Asb + (rm + mi * 16 + fr) * 32 + fk);
#pragma unroll
        for (int ni = 0; ni < 4; ++ni)
            bv[ni] = *(const bf16x8*)(Bsb + (wn * 64 + ni * 16 + fr) * 32 + fk);
#pragma unroll
        for (int mi = 0; mi < MI; ++mi)
#pragma unroll
            for (int ni = 0; ni < 4; ++ni)
                acc[mi][ni] = __builtin_amdgcn_mfma_f32_16x16x32_bf16(
                    af[mi], bv[ni], acc[mi][ni], 0, 0, 0);
    };

    // ---- 2-buffer pipelined K loop (nk even for all shapes used: K=512/2048) ----
    int nk = K >> 5;
    stage(0, 0);
    __syncthreads();
    for (int kt = 0; kt < nk; kt += 2) {
        if (kt + 1 < nk) stage(kt + 1, PL);
        compute(0);
        __syncthreads();
        if (kt + 2 < nk) stage(kt + 2, 0);
        compute(PL);
        __syncthreads();
    }

    int cc = lane & 15, cr = (lane >> 4) * 4;
    if (yq) {
        // ---- fused-Yt epilogue (s7): num at even cols, den at odd cols ----
        long qb = (long)bz * (long)(T_ * D_);
#pragma unroll
        for (int mi = 0; mi < MI; ++mi) {
#pragma unroll
            for (int ni = 0; ni < 4; ++ni) {
                int row0 = m0 + rm + mi * 16 + cr;
                int col = n0 + wn * 64 + ni * 16 + cc;
                int d = col >> 1;
#pragma unroll
                for (int r = 0; r < 4; ++r) {
                    float v = acc[mi][ni][r];
                    float other = __shfl_xor(v, 1);
                    if (!(lane & 1)) {
                        long qi = qb + (long)(row0 + r) * D_ + d;
                        float sq = ldf((const bf16*)yq, qi);
                        yq[qi] = __float2bfloat16(sq * v / other);
                    }
                }
            }
        }
        return;
    }
    long cbase = (long)bz * bsC;
#pragma unroll
    for (int mi = 0; mi < MI; ++mi) {
#pragma unroll
        for (int ni = 0; ni < 4; ++ni) {
            int row0 = m0 + rm + mi * 16 + cr;
            int col = n0 + wn * 64 + ni * 16 + cc;
            float bvl;
            long colterm;
            int md, rowstride;
            if (planeStride) {
                int plane = col >> 9;
                int c2 = col & 511;
                const float* bp = (plane == 0) ? b0 : ((plane == 1) ? b1 : b2);
                bvl = bp[c2];
                md = (modes >> (2 * plane)) & 3;
                colterm = (long)plane * planeStride + c2;
                rowstride = 512;
            } else {
                bvl = b0 ? b0[col] : 0.0f;
                md = modes & 3;
                colterm = col;
                rowstride = N;
            }
#pragma unroll
            for (int r = 0; r < 4; ++r) {
                float v = acc[mi][ni][r] + bvl;
                if (md == 1) v = 1.0f / (1.0f + __expf(-v));
                else if (md == 2) v = gelu_f(v);
                long idx;
                if (PCK) idx = cbase + poff(row0 + r, col, N);
                else     idx = cbase + (long)(row0 + r) * rowstride + colterm;
                if (resf) v += resf[idx];
                if (resb) v += ldf(resb, idx);
                if (Cf) Cf[idx] = v;
                else Cb[idx] = __float2bfloat16(v);
            }
        }
    }
}

extern "C" void kernel_launch(void* const* d_in, const int* in_sizes, int n_in,
                              void* d_out, int out_size, void* d_ws, size_t ws_size,
                              hipStream_t stream) {
    const float* x    = (const float*)d_in[0];
    const float* ln1g = (const float*)d_in[1];
    const float* ln1b = (const float*)d_in[2];
    const float* Wk   = (const float*)d_in[3];
    const float* bk   = (const float*)d_in[4];
    const float* Wv   = (const float*)d_in[5];
    const float* bv   = (const float*)d_in[6];
    const float* Wq   = (const float*)d_in[7];
    const float* bq   = (const float*)d_in[8];
    const float* w    = (const float*)d_in[9];
    const float* Wo   = (const float*)d_in[10];
    const float* bo   = (const float*)d_in[11];
    const float* ln2g = (const float*)d_in[12];
    const float* ln2b = (const float*)d_in[13];
    const float* W1   = (const float*)d_in[14];
    const float* b1   = (const float*)d_in[15];
    const float* W2   = (const float*)d_in[16];
    const float* b2   = (const float*)d_in[17];
    float* out = (float*)d_out;

    const long S_BTD = (long)B_ * T_ * D_;      // 8,388,608
    const long S_TD  = (long)T_ * D_;           // 1,048,576
    const long S_TT  = (long)T_ * T_;           // 4,194,304
    const long S_B2D = (long)B_ * T_ * 2 * D_;  // 16,777,216
    const long S_DD  = (long)D_ * D_;           // 262,144

    // Workspace (bf16 elems unless noted) ~136 MB:
    bf16* h1     = (bf16*)d_ws;            // later h2 (both PACKED)
    bf16* outres = h1 + S_BTD;             // linear
    bf16* ew     = outres + S_BTD;         // PACKED
    bf16* KVQ    = ew + S_TT;              // K|V|Q planes (3*S_BTD), linear
    bf16* kv2t   = KVQ + 3 * S_BTD;        // S_B2D, PACKED+interleaved per batch
    bf16* mk     = kv2t + S_B2D;           // S_TD bf16
    bf16* WkT    = mk + 2 * S_TD;          // all weights PACKED
    bf16* WvT    = WkT + S_DD;
    bf16* WqT    = WvT + S_DD;
    bf16* WoT    = WqT + S_DD;
    bf16* W1T    = WoT + S_DD;             // [H,D]
    bf16* W2T    = W1T + (long)D_ * H_;    // [D,H]
    bf16* Kb  = KVQ;
    bf16* Vb  = KVQ + S_BTD;
    bf16* Qb  = KVQ + 2 * S_BTD;           // sigQ linear, then Yt in place (s7)
    bf16* hH  = KVQ;                       // PACKED; spans K|V planes (dead) + more
    bf16* h2  = h1;

    const int M = B_ * T_;  // 16384

    // 1. batched weight transposes (packed output)
    WT6 p;
    p.src[0] = Wk; p.src[1] = Wv; p.src[2] = Wq; p.src[3] = Wo; p.src[4] = W1; p.src[5] = W2;
    p.dst[0] = WkT; p.dst[1] = WvT; p.dst[2] = WqT; p.dst[3] = WoT; p.dst[4] = W1T; p.dst[5] = W2T;
    p.K[0] = p.K[1] = p.K[2] = p.K[3] = 512; p.K[4] = 512; p.K[5] = 2048;
    p.N[0] = p.N[1] = p.N[2] = p.N[3] = 512; p.N[4] = 2048; p.N[5] = 512;
    wtrans6_kernel<<<dim3(32, 32, 6), 256, 0, stream>>>(p);
    // 2. h1 = LN1(x), packed
    ln_kernel<float, true><<<M, 256, 0, stream>>>(x, ln1g, ln1b, h1);
    // 3. K|V|sigQ GEMM: planes linear -> Kb,Vb,Qb (sigmoid on Q plane)
    mfma_gemm<128, 3><<<dim3(1536 / 128, M / 128, 1), 256, 0, stream>>>(
        h1, WkT, bk, bv, bq, Kb, nullptr, nullptr, nullptr, nullptr,
        M, 1536, D_, (1 << 4), 0, 0, S_BTD);
    // 4. mk = max_b K (bf16); 5. kv2t packed + interleaved
    maxk_kernel<<<S_TD / 256, 256, 0, stream>>>(Kb, mk);
    kv2t_kernel<<<dim3(T_ / 64, D_ / 64, B_), 256, 0, stream>>>(Kb, Vb, mk, kv2t);
    // 6. exp_w (packed)
    expw_kernel<<<T_, 256, 0, stream>>>(w, ew);
    // 7. FUSED: Yt = sigQ * (ew@evK*V)/(ew@evK), written in place into Qb.
    //    (eliminates yt_kernel + the 33.6MB nd round-trip)
    mfma_gemm<128, 3><<<dim3(1024 / 128, T_ / 128, B_), 256, 0, stream>>>(
        ew, kv2t, nullptr, nullptr, nullptr, nullptr, nullptr, nullptr, nullptr, Qb,
        T_, 1024, T_, 0, (long)1024 * T_, 0, 0);
    // 9. out = Yt@Wo + bo + x, C linear + f32 residual
    mfma_gemm<128, 2><<<dim3(D_ / 128, M / 128, 1), 256, 0, stream>>>(
        Qb, WoT, bo, nullptr, nullptr, outres, nullptr, nullptr, x, nullptr,
        M, D_, D_, 0, 0, 0, 0);
    // 10. h2 = LN2(out), packed
    ln_kernel<bf16, true><<<M, 256, 0, stream>>>(outres, ln2g, ln2b, h2);
    // 11. hH = gelu(h2@W1 + b1), C PACKED (= step-12 A)
    mfma_gemm<128, 7><<<dim3(H_ / 128, M / 128, 1), 256, 0, stream>>>(
        h2, W1T, b1, nullptr, nullptr, hH, nullptr, nullptr, nullptr, nullptr,
        M, H_, D_, 2, 0, 0, 0);
    // 12. y = gelu(hH@W2 + b2) + out -> f32 d_out
    mfma_gemm<128, 3><<<dim3(D_ / 128, M / 128, 1), 256, 0, stream>>>(
        hH, W2T, b2, nullptr, nullptr, nullptr, out, outres, nullptr, nullptr,
        M, D_, H_, 2, 0, 0, 0);
}